// Round 13
// baseline (321.993 us; speedup 1.0000x reference)
//
#include <hip/hip_runtime.h>

// ---------------------------------------------------------------------------
// Barrier-free wave-autonomous design, TRANSPOSED MFMA epilogue.
// Round 13: retry of the 2-tile ILP pairing (R5) on the R12 base, now that
// R6/R7 proved R5's failure was the __launch_bounds__ VGPR cap (84), not the
// pairing. R12's post-mortem: DS-write deletion neutral, occupancy neutral ->
// stall-bound (VALU floor 172k cyc vs 382k kernel cyc, ~2.3-3.5 waves/SIMD).
// Fix = ILP within the wave:
//  - each stage processes tiles as a RUNTIME pair loop (tb=0,32) + single
//    tile 64. Within a pair, +16-row literal offsets are AA-provably
//    disjoint -> two independent read->MFMA->LN->write chains interleave;
//    across pairs, runtime tb blocks hoisting -> live state ~2 tiles.
//  - launch_bounds(128,2): VGPR cap 256 >> expected ~110-145. NO forced
//    spill (anchor: WRITE_SIZE stays 25.2MB).
// Carried from R12 (both hardware-validated): pre2<>L0W1 fusion (kT blocks
// 1/2, fused bias at OFF_FB), compact pooled pad (cols 64..71, bcast k-hi).
// ---------------------------------------------------------------------------

#define ASTR 72   // act row stride in shorts (64 feats + 8 pad = pooled slot)

typedef short v8s __attribute__((ext_vector_type(8)));
typedef float v4f __attribute__((ext_vector_type(4)));

#define MFMA __builtin_amdgcn_mfma_f32_16x16x32_bf16

// ws layout (offsets in shorts)
#define OFF_PW1 0                        // 64 x 32 (K=16 zero-padded to 32)
#define OFF_FB  2048                     // 64 f32 fused bias (in old PW2 slot)
#define OFF_LW1(L) (6144 + (L) * 6144)   // 64 x 64  (L=0 holds FUSED pw2@w1a)
#define OFF_LW2(L) (OFF_LW1(L) + 4096)   // 32 x 64
#define OFF_OW1 24576                    // 64 x 64
#define OFF_OW2 28672                    // 128 x 64   (end = 36864 shorts)

__device__ __forceinline__ short bfb(float v) {
  __bf16 b = (__bf16)v;
  return __builtin_bit_cast(short, b);
}

// ---- kT: transpose weights into bf16 B-fragment layout in ws ----
__global__ void kT(const float* __restrict__ pw1, const float* __restrict__ pw2,
                   const float* __restrict__ w1a, const float* __restrict__ w2a,
                   const float* __restrict__ w1b, const float* __restrict__ w2b,
                   const float* __restrict__ w1c, const float* __restrict__ w2c,
                   const float* __restrict__ ow1, const float* __restrict__ ow2,
                   const float* __restrict__ pb2, const float* __restrict__ b1a,
                   short* __restrict__ ws) {
  if (blockIdx.x == 1) {
    float* fb = (float*)(ws + OFF_FB);
    for (int f = threadIdx.x; f < 64; f += blockDim.x) {
      float s = b1a[f];
      for (int m = 0; m < 64; ++m) s = fmaf(pb2[m], w1a[m * 64 + f], s);
      fb[f] = s;
    }
    return;
  }
  if (blockIdx.x == 2) {
    const int off = OFF_LW1(0);
    const int total = 64 * 8;
    for (int i = threadIdx.x; i < total; i += blockDim.x) {
      const int f = i % 64;
      const int kq = i / 64;
      v8s h;
#pragma unroll
      for (int j = 0; j < 8; ++j) {
        const int k = kq * 8 + j;
        float s = 0.f;
        for (int m = 0; m < 64; ++m) s = fmaf(pw2[k * 64 + m], w1a[m * 64 + f], s);
        h[j] = bfb(s);
      }
      *(v8s*)(ws + off + f * 64 + kq * 8) = h;
    }
    return;
  }
  const float* W; int K, F, Kpad, off;
  switch (blockIdx.x) {
    case 0: W = pw1; K = 16; F = 64;  Kpad = 32; off = OFF_PW1; break;
    case 3: W = w2a; K = 64; F = 32;  Kpad = 64; off = OFF_LW2(0); break;
    case 4: W = w1b; K = 64; F = 64;  Kpad = 64; off = OFF_LW1(1); break;
    case 5: W = w2b; K = 64; F = 32;  Kpad = 64; off = OFF_LW2(1); break;
    case 6: W = w1c; K = 64; F = 64;  Kpad = 64; off = OFF_LW1(2); break;
    case 7: W = w2c; K = 64; F = 32;  Kpad = 64; off = OFF_LW2(2); break;
    case 8: W = ow1; K = 64; F = 64;  Kpad = 64; off = OFF_OW1; break;
    default: W = ow2; K = 64; F = 128; Kpad = 64; off = OFF_OW2; break;
  }
  const int total = F * (Kpad >> 3);
  for (int i = threadIdx.x; i < total; i += blockDim.x) {
    const int f = i % F;
    const int kq = i / F;
    v8s h;
#pragma unroll
    for (int j = 0; j < 8; ++j) {
      const int k = kq * 8 + j;
      h[j] = bfb((k < K) ? W[k * F + f] : 0.f);
    }
    *(v8s*)(ws + off + f * Kpad + kq * 8) = h;
  }
}

__device__ __forceinline__ v8s ldv(const short* p) { return *(const v8s*)p; }

// LayerNorm(64)+ReLU, features in-lane; short4 (b64) writes.
__device__ __forceinline__ void lnT_write(short* Aw, int tb, int col, int quad,
                                          v4f* acc, const v4f* g4,
                                          const v4f* be4) {
  float mu = 0.f, sq = 0.f;
#pragma unroll
  for (int t = 0; t < 4; ++t)
#pragma unroll
    for (int r = 0; r < 4; ++r) {
      mu += acc[t][r];
      sq = fmaf(acc[t][r], acc[t][r], sq);
    }
  mu += __shfl_xor(mu, 16); mu += __shfl_xor(mu, 32);
  sq += __shfl_xor(sq, 16); sq += __shfl_xor(sq, 32);
  mu *= (1.0f / 64.0f);
  const float var = sq * (1.0f / 64.0f) - mu * mu;
  const float rs = rsqrtf(var + 1e-5f);
#pragma unroll
  for (int t = 0; t < 4; ++t) {
    short4 s;
#pragma unroll
    for (int r = 0; r < 4; ++r) {
      float v = fmaf((acc[t][r] - mu) * rs, g4[t][r], be4[t][r]);
      ((short*)&s)[r] = bfb(fmaxf(v, 0.f));
    }
    *(short4*)(Aw + (tb + col) * ASTR + t * 16 + quad * 4) = s;
  }
}

template <int NT>
__device__ __forceinline__ void plainT_write(short* Aw, int tb, int col,
                                             int quad, v4f* acc) {
#pragma unroll
  for (int t = 0; t < NT; ++t) {
    short4 s;
#pragma unroll
    for (int r = 0; r < 4; ++r) ((short*)&s)[r] = bfb(acc[t][r]);
    *(short4*)(Aw + (tb + col) * ASTR + t * 16 + quad * 4) = s;
  }
}

// load B-fragments for one tile; SPLIT: k-hi fragment from pooled pad (bcast).
template <int KS, bool SPLIT>
__device__ __forceinline__ void ldfrag(const short* A, int tb, int col,
                                       int quad, v8s* a) {
#pragma unroll
  for (int ks = 0; ks < KS; ++ks) {
    if (SPLIT && ks == KS - 1) {
      const int cl = ((tb + col) * 205) >> 12;       // node/20 for node<80
      a[ks] = ldv(A + (cl * 4 + quad) * ASTR + 64);  // pad cols 64..71
    } else {
      a[ks] = ldv(A + (tb + col) * ASTR + ks * 32 + quad * 8);
    }
  }
}

// ---- pair: W1(+LN) for tiles (tb, tb+16): two independent chains ----
template <int KS, bool SPLIT>
__device__ __forceinline__ void pairMMLN(short* A, int tb, const v8s* Wf,
                                         const v4f* b4, const v4f* g4,
                                         const v4f* be4, int col, int quad) {
  v8s a0[KS], a1[KS];
  ldfrag<KS, SPLIT>(A, tb, col, quad, a0);
  ldfrag<KS, SPLIT>(A, tb + 16, col, quad, a1);
  v4f c0[4], c1[4];
#pragma unroll
  for (int t = 0; t < 4; ++t) { c0[t] = b4[t]; c1[t] = b4[t]; }
#pragma unroll
  for (int ks = 0; ks < KS; ++ks)
#pragma unroll
    for (int t = 0; t < 4; ++t) {
      c0[t] = MFMA(Wf[t * KS + ks], a0[ks], c0[t], 0, 0, 0);
      c1[t] = MFMA(Wf[t * KS + ks], a1[ks], c1[t], 0, 0, 0);
    }
  lnT_write(A, tb, col, quad, c0, g4, be4);
  lnT_write(A, tb + 16, col, quad, c1, g4, be4);
}

template <int KS, bool SPLIT>
__device__ __forceinline__ void singleMMLN(short* A, int tb, const v8s* Wf,
                                           const v4f* b4, const v4f* g4,
                                           const v4f* be4, int col, int quad) {
  v8s a0[KS];
  ldfrag<KS, SPLIT>(A, tb, col, quad, a0);
  v4f c0[4];
#pragma unroll
  for (int t = 0; t < 4; ++t) c0[t] = b4[t];
#pragma unroll
  for (int ks = 0; ks < KS; ++ks)
#pragma unroll
    for (int t = 0; t < 4; ++t)
      c0[t] = MFMA(Wf[t * KS + ks], a0[ks], c0[t], 0, 0, 0);
  lnT_write(A, tb, col, quad, c0, g4, be4);
}

// ---- pair: plain NT-wide matmul + write (W2: NT=2) ----
template <int NT>
__device__ __forceinline__ void pairMMP(short* A, int tb, const v8s* Wf,
                                        const v4f* b4, int col, int quad) {
  v8s a0[2], a1[2];
  ldfrag<2, false>(A, tb, col, quad, a0);
  ldfrag<2, false>(A, tb + 16, col, quad, a1);
  v4f c0[NT], c1[NT];
#pragma unroll
  for (int t = 0; t < NT; ++t) { c0[t] = b4[t]; c1[t] = b4[t]; }
#pragma unroll
  for (int ks = 0; ks < 2; ++ks)
#pragma unroll
    for (int t = 0; t < NT; ++t) {
      c0[t] = MFMA(Wf[t * 2 + ks], a0[ks], c0[t], 0, 0, 0);
      c1[t] = MFMA(Wf[t * 2 + ks], a1[ks], c1[t], 0, 0, 0);
    }
  plainT_write<NT>(A, tb, col, quad, c0);
  plainT_write<NT>(A, tb + 16, col, quad, c1);
}

template <int NT>
__device__ __forceinline__ void singleMMP(short* A, int tb, const v8s* Wf,
                                          const v4f* b4, int col, int quad) {
  v8s a0[2];
  ldfrag<2, false>(A, tb, col, quad, a0);
  v4f c0[NT];
#pragma unroll
  for (int t = 0; t < NT; ++t) c0[t] = b4[t];
#pragma unroll
  for (int ks = 0; ks < 2; ++ks)
#pragma unroll
    for (int t = 0; t < NT; ++t)
      c0[t] = MFMA(Wf[t * 2 + ks], a0[ks], c0[t], 0, 0, 0);
  plainT_write<NT>(A, tb, col, quad, c0);
}

// ---- kF: the whole network, one wave = 4 clusters, zero barriers ----
__global__ void __launch_bounds__(128, 2)
kF(const float* __restrict__ x, const int* __restrict__ batch,
   const short* __restrict__ wsW,
   const float* __restrict__ pb1, const float* __restrict__ pg,
   const float* __restrict__ pbe,
   const float* __restrict__ b1a, const float* __restrict__ ga,
   const float* __restrict__ bea, const float* __restrict__ b2a,
   const float* __restrict__ b1b, const float* __restrict__ gb,
   const float* __restrict__ beb, const float* __restrict__ b2b,
   const float* __restrict__ b1c, const float* __restrict__ gc_,
   const float* __restrict__ bec, const float* __restrict__ b2c,
   const float* __restrict__ ob1, const float* __restrict__ og,
   const float* __restrict__ obe, const float* __restrict__ ob2,
   float* __restrict__ out, int C) {
  __shared__ __align__(16) short act[2 * 80 * ASTR];   // 23040 B
  const int tid = threadIdx.x;
  const int lane = tid & 63;
  const int wave = tid >> 6;
  const int col = lane & 15;
  const int quad = lane >> 4;
  const int cbase = blockIdx.x * 8 + wave * 4;
  if (cbase >= C) return;
  const int nc = min(4, C - cbase);
  const int nrows = nc * 20;
  const int ntiles = (nrows + 15) >> 4;
  short* A = act + wave * 80 * ASTR;

  // ---- load x -> bf16 cols 0..15, zero cols 16..31 ----
  {
    const float4* x4 = (const float4*)x;
    const long nb = (long)cbase * 20;
    const short4 z = {0, 0, 0, 0};
    for (int i = lane; i < nrows * 4; i += 64) {
      const int row = i >> 2, e = i & 3;
      float4 v = x4[(nb + row) * 4 + e];
      short4 s = {bfb(v.x), bfb(v.y), bfb(v.z), bfb(v.w)};
      *(short4*)(A + row * ASTR + e * 4) = s;
      *(short4*)(A + row * ASTR + 16 + e * 4) = z;
    }
    if (nrows < ntiles * 16) {
      for (int i = lane; i < (ntiles * 16 - nrows) * 18; i += 64) {
        const int row = nrows + i / 18, e = i % 18;
        *(short4*)(A + row * ASTR + e * 4) = z;
      }
    }
  }

  // ---- pre-MLP stage 1: 16(pad32) -> 64, LN, ReLU (paired tiles) ----
  {
    v8s Wf[4]; v4f b4[4], g4[4], be4[4];
#pragma unroll
    for (int t = 0; t < 4; ++t) {
      Wf[t] = ldv(wsW + OFF_PW1 + (t * 16 + col) * 32 + quad * 8);
      b4[t]  = *(const v4f*)(pb1 + t * 16 + quad * 4);
      g4[t]  = *(const v4f*)(pg  + t * 16 + quad * 4);
      be4[t] = *(const v4f*)(pbe + t * 16 + quad * 4);
    }
    for (int tb = 0; tb < 64; tb += 32)
      pairMMLN<1, false>(A, tb, Wf, b4, g4, be4, col, quad);
    singleMMLN<1, false>(A, 64, Wf, b4, g4, be4, col, quad);
  }

  // (pre-MLP stage 2 fused into layer 0's W1 -- see kT blocks 1/2)

  // ---- 3 subgraph layers (per-L pointers; paired tiles) ----
  const float* fb = (const float*)(wsW + OFF_FB);   // fused bias for L0-W1
  const float* B1p[3] = {fb, b1b, b1c};
  const float* Gp[3]  = {ga, gb, gc_};
  const float* BEp[3] = {bea, beb, bec};
  const float* B2p[3] = {b2a, b2b, b2c};

  for (int L = 0; L < 3; ++L) {
    v8s W1f[8], W2f[4];
    v4f b14[4], g4[4], be4[4], b24[2];
    const short* w1 = wsW + OFF_LW1(L);
    const short* w2 = wsW + OFF_LW2(L);
#pragma unroll
    for (int t = 0; t < 4; ++t) {
#pragma unroll
      for (int ks = 0; ks < 2; ++ks)
        W1f[t * 2 + ks] = ldv(w1 + (t * 16 + col) * 64 + ks * 32 + quad * 8);
      b14[t] = *(const v4f*)(B1p[L] + t * 16 + quad * 4);
      g4[t]  = *(const v4f*)(Gp[L]  + t * 16 + quad * 4);
      be4[t] = *(const v4f*)(BEp[L] + t * 16 + quad * 4);
    }
#pragma unroll
    for (int t = 0; t < 2; ++t) {
#pragma unroll
      for (int ks = 0; ks < 2; ++ks)
        W2f[t * 2 + ks] = ldv(w2 + (t * 16 + col) * 64 + ks * 32 + quad * 8);
      b24[t] = *(const v4f*)(B2p[L] + t * 16 + quad * 4);
    }
    if (L == 0) {
      for (int tb = 0; tb < 64; tb += 32) {
        pairMMLN<2, false>(A, tb, W1f, b14, g4, be4, col, quad);
        pairMMP<2>(A, tb, W2f, b24, col, quad);
      }
      singleMMLN<2, false>(A, 64, W1f, b14, g4, be4, col, quad);
      singleMMP<2>(A, 64, W2f, b24, col, quad);
    } else {
      for (int tb = 0; tb < 64; tb += 32) {
        pairMMLN<2, true>(A, tb, W1f, b14, g4, be4, col, quad);
        pairMMP<2>(A, tb, W2f, b24, col, quad);
      }
      singleMMLN<2, true>(A, 64, W1f, b14, g4, be4, col, quad);
      singleMMP<2>(A, 64, W2f, b24, col, quad);
    }
    // ---- intra-wave pooling: 4 clusters x 16 uint-cols ----
    {
      const int cl = quad, jp = col;
      if (cl < nc) {
        const uint* AU = (const uint*)A;
        float m0 = -3.4e38f, m1 = -3.4e38f;
#pragma unroll
        for (int r = 0; r < 20; ++r) {
          const uint v = AU[(cl * 20 + r) * (ASTR / 2) + jp];
          m0 = fmaxf(m0, __builtin_bit_cast(float, v << 16));
          m1 = fmaxf(m1, __builtin_bit_cast(float, v & 0xFFFF0000u));
        }
        const uint pv = (uint)(unsigned short)bfb(m0) |
                        ((uint)(unsigned short)bfb(m1) << 16);
        uint* AW = (uint*)A;
        if (L < 2) {
          // compact: row cl*4+u's pad uints 32..35 hold pooled uints 4u..4u+3
          AW[(cl * 4 + (jp >> 2)) * (ASTR / 2) + 32 + (jp & 3)] = pv;
        } else {
          // segmax(concat[h,pooled]) == [pooled,pooled] -> rows 0..3 = pooled
          AW[cl * (ASTR / 2) + jp] = pv;
          AW[cl * (ASTR / 2) + 16 + jp] = pv;
        }
      }
    }
  }

  // ---- fused output MLP on rows 0..15 (rows 0..nc-1 valid) ----
  {
    v8s Wf[8]; v4f b4[4], g4[4], be4[4];
#pragma unroll
    for (int t = 0; t < 4; ++t) {
#pragma unroll
      for (int ks = 0; ks < 2; ++ks)
        Wf[t * 2 + ks] = ldv(wsW + OFF_OW1 + (t * 16 + col) * 64 + ks * 32 + quad * 8);
      b4[t]  = *(const v4f*)(ob1 + t * 16 + quad * 4);
      g4[t]  = *(const v4f*)(og  + t * 16 + quad * 4);
      be4[t] = *(const v4f*)(obe + t * 16 + quad * 4);
    }
    singleMMLN<2, false>(A, 0, Wf, b4, g4, be4, col, quad);
  }
  {
    v4f acc[8];
    const v8s bb0 = ldv(A + col * ASTR + quad * 8);
    const v8s bb1 = ldv(A + col * ASTR + 32 + quad * 8);
#pragma unroll
    for (int half = 0; half < 2; ++half) {
      v8s Wf[8];
#pragma unroll
      for (int t = 0; t < 4; ++t)
#pragma unroll
        for (int ks = 0; ks < 2; ++ks)
          Wf[t * 2 + ks] = ldv(wsW + OFF_OW2 +
                             ((half * 4 + t) * 16 + col) * 64 + ks * 32 + quad * 8);
#pragma unroll
      for (int t = 0; t < 4; ++t) {
        v4f a = *(const v4f*)(ob2 + (half * 4 + t) * 16 + quad * 4);
        a = MFMA(Wf[t * 2], bb0, a, 0, 0, 0);
        a = MFMA(Wf[t * 2 + 1], bb1, a, 0, 0, 0);
        acc[half * 4 + t] = a;
      }
    }
    // L2 norm over 128 feats (32 in-lane + cross-quad)
    float sq = 0.f;
#pragma unroll
    for (int t = 0; t < 8; ++t)
#pragma unroll
      for (int r = 0; r < 4; ++r) sq = fmaf(acc[t][r], acc[t][r], sq);
    sq += __shfl_xor(sq, 16); sq += __shfl_xor(sq, 32);
    const float inv = 1.0f / fmaxf(sqrtf(sq), 1e-12f);
    if (col < nc) {
      const long gcl = cbase + col;
#pragma unroll
      for (int t = 0; t < 8; ++t) {
        float4 v = {acc[t][0] * inv, acc[t][1] * inv,
                    acc[t][2] * inv, acc[t][3] * inv};
        *(float4*)(out + gcl * 128 + t * 16 + quad * 4) = v;
      }
      if (quad == 0) out[(long)C * 128 + gcl] = (float)batch[gcl * 20];
    }
  }
}

extern "C" void kernel_launch(void* const* d_in, const int* in_sizes, int n_in,
                              void* d_out, int out_size, void* d_ws, size_t ws_size,
                              hipStream_t stream) {
  const float* x     = (const float*)d_in[0];
  const int*   batch = (const int*)d_in[2];
  const float* pw1 = (const float*)d_in[3];
  const float* pb1 = (const float*)d_in[4];
  const float* pg  = (const float*)d_in[5];
  const float* pbe = (const float*)d_in[6];
  const float* pw2 = (const float*)d_in[7];
  const float* pb2 = (const float*)d_in[8];
  const float* w1a = (const float*)d_in[9];
  const float* b1a = (const float*)d_in[10];
  const float* ga  = (const float*)d_in[11];
  const float* bea = (const float*)d_in[12];
  const float* w2a = (const float*)d_in[13];
  const float* b2a = (const float*)d_in[14];
  const float* w1b = (const float*)d_in[15];
  const float* b1b = (const float*)d_in[16];
  const float* gb  = (const float*)d_in[17];
  const float* beb = (const float*)d_in[18];
  const float* w2b = (const float*)d_in[19];
  const float* b2b = (const float*)d_in[20];
  const float* w1c = (const float*)d_in[21];
  const float* b1c = (const float*)d_in[22];
  const float* gc  = (const float*)d_in[23];
  const float* bec = (const float*)d_in[24];
  const float* w2c = (const float*)d_in[25];
  const float* b2c = (const float*)d_in[26];
  const float* ow1 = (const float*)d_in[27];
  const float* ob1 = (const float*)d_in[28];
  const float* og  = (const float*)d_in[29];
  const float* obe = (const float*)d_in[30];
  const float* ow2 = (const float*)d_in[31];
  const float* ob2 = (const float*)d_in[32];

  const int N = in_sizes[0] / 16;
  const int C = N / 20;
  short* ws16 = (short*)d_ws;
  float* out = (float*)d_out;

  hipLaunchKernelGGL(kT, dim3(10), dim3(256), 0, stream,
                     pw1, pw2, w1a, w2a, w1b, w2b, w1c, w2c, ow1, ow2,
                     pb2, b1a, ws16);

  const int blocks = (C + 7) / 8;   // 8 clusters per block (2 waves x 4)
  hipLaunchKernelGGL(kF, dim3(blocks), dim3(128), 0, stream,
                     x, batch, (const short*)ws16,
                     pb1, pg, pbe,
                     b1a, ga, bea, b2a,
                     b1b, gb, beb, b2b,
                     b1c, gc, bec, b2c,
                     ob1, og, obe, ob2,
                     out, C);
}

// Round 14
// 302.935 us; speedup vs baseline: 1.0629x; 1.0629x over previous
//
#include <hip/hip_runtime.h>

// ---------------------------------------------------------------------------
// Barrier-free wave-autonomous design, TRANSPOSED MFMA epilogue.
// Round 14 = R12 base (158.6us kF: pre2<>L0W1 fusion + compact pooled pad)
// + x-staging stage DELETED. R13 post-mortem refuted in-wave ILP (uncapped
// pairing regressed: occupancy 29->20%); the only lever that has paid is
// work deletion (R9). This round deletes the largest remaining stage:
//   pre1's B-fragment is directly loadable from GLOBAL: lane (col, quad<2)
//   needs 8 contiguous fp32 (features quad*8..+7 of node T*16+col) = two
//   float4 loads; quads 2/3 pass the K-pad zeros in-register (exact: PW1
//   rows 16..31 are zero in ws). So the x->LDS transpose stage (5 global +
//   20 ds_write + ~30 VALU per lane) is deleted outright; pre1 converts
//   fp32->bf16 in registers and feeds MFMA directly. y1 still lands in LDS
//   via lnT_write; everything downstream is byte-identical to R12.
// ---------------------------------------------------------------------------

#define ASTR 72   // act row stride in shorts (64 feats + 8 pad = pooled slot)

typedef short v8s __attribute__((ext_vector_type(8)));
typedef float v4f __attribute__((ext_vector_type(4)));

#define MFMA __builtin_amdgcn_mfma_f32_16x16x32_bf16

// ws layout (offsets in shorts)
#define OFF_PW1 0                        // 64 x 32 (K=16 zero-padded to 32)
#define OFF_FB  2048                     // 64 f32 fused bias (in old PW2 slot)
#define OFF_LW1(L) (6144 + (L) * 6144)   // 64 x 64  (L=0 holds FUSED pw2@w1a)
#define OFF_LW2(L) (OFF_LW1(L) + 4096)   // 32 x 64
#define OFF_OW1 24576                    // 64 x 64
#define OFF_OW2 28672                    // 128 x 64   (end = 36864 shorts)

__device__ __forceinline__ short bfb(float v) {
  __bf16 b = (__bf16)v;
  return __builtin_bit_cast(short, b);
}

// ---- kT: transpose weights into bf16 B-fragment layout in ws ----
// block 1: fused bias pb2@w1a + b1a (f32 -> OFF_FB)
// block 2: fused weight pw2@w1a (fp32 accum -> bf16 fragments -> LW1(0))
__global__ void kT(const float* __restrict__ pw1, const float* __restrict__ pw2,
                   const float* __restrict__ w1a, const float* __restrict__ w2a,
                   const float* __restrict__ w1b, const float* __restrict__ w2b,
                   const float* __restrict__ w1c, const float* __restrict__ w2c,
                   const float* __restrict__ ow1, const float* __restrict__ ow2,
                   const float* __restrict__ pb2, const float* __restrict__ b1a,
                   short* __restrict__ ws) {
  if (blockIdx.x == 1) {
    float* fb = (float*)(ws + OFF_FB);
    for (int f = threadIdx.x; f < 64; f += blockDim.x) {
      float s = b1a[f];
      for (int m = 0; m < 64; ++m) s = fmaf(pb2[m], w1a[m * 64 + f], s);
      fb[f] = s;
    }
    return;
  }
  if (blockIdx.x == 2) {
    const int off = OFF_LW1(0);
    const int total = 64 * 8;
    for (int i = threadIdx.x; i < total; i += blockDim.x) {
      const int f = i % 64;
      const int kq = i / 64;
      v8s h;
#pragma unroll
      for (int j = 0; j < 8; ++j) {
        const int k = kq * 8 + j;
        float s = 0.f;
        for (int m = 0; m < 64; ++m) s = fmaf(pw2[k * 64 + m], w1a[m * 64 + f], s);
        h[j] = bfb(s);
      }
      *(v8s*)(ws + off + f * 64 + kq * 8) = h;
    }
    return;
  }
  const float* W; int K, F, Kpad, off;
  switch (blockIdx.x) {
    case 0: W = pw1; K = 16; F = 64;  Kpad = 32; off = OFF_PW1; break;
    case 3: W = w2a; K = 64; F = 32;  Kpad = 64; off = OFF_LW2(0); break;
    case 4: W = w1b; K = 64; F = 64;  Kpad = 64; off = OFF_LW1(1); break;
    case 5: W = w2b; K = 64; F = 32;  Kpad = 64; off = OFF_LW2(1); break;
    case 6: W = w1c; K = 64; F = 64;  Kpad = 64; off = OFF_LW1(2); break;
    case 7: W = w2c; K = 64; F = 32;  Kpad = 64; off = OFF_LW2(2); break;
    case 8: W = ow1; K = 64; F = 64;  Kpad = 64; off = OFF_OW1; break;
    default: W = ow2; K = 64; F = 128; Kpad = 64; off = OFF_OW2; break;
  }
  const int total = F * (Kpad >> 3);
  for (int i = threadIdx.x; i < total; i += blockDim.x) {
    const int f = i % F;
    const int kq = i / F;
    v8s h;
#pragma unroll
    for (int j = 0; j < 8; ++j) {
      const int k = kq * 8 + j;
      h[j] = bfb((k < K) ? W[k * F + f] : 0.f);
    }
    *(v8s*)(ws + off + f * Kpad + kq * 8) = h;
  }
}

// Transposed matmul over one 16-node tile: acc[t] covers features t*16..+15.
template <int NT, int KS>
__device__ __forceinline__ void mmT(const short* A, int tb, const v8s* Wf,
                                    const v4f* bias4, int col, int quad,
                                    v4f* acc) {
#pragma unroll
  for (int t = 0; t < NT; ++t) acc[t] = bias4[t];
#pragma unroll
  for (int ks = 0; ks < KS; ++ks) {
    const v8s b = *(const v8s*)(A + (tb + col) * ASTR + ks * 32 + quad * 8);
#pragma unroll
    for (int t = 0; t < NT; ++t)
      acc[t] = MFMA(Wf[t * KS + ks], b, acc[t], 0, 0, 0);
  }
}

// Split matmul: k=0..31 from act row (h), k=32..63 from pooled pad (bcast).
template <int NT>
__device__ __forceinline__ void mmT_split(const short* A, int tb,
                                          const v8s* Wf, const v4f* bias4,
                                          int col, int quad, v4f* acc) {
  const int node = tb + col;
  const int cl = (node * 205) >> 12;                 // node/20 for node<80
  const v8s b0 = *(const v8s*)(A + node * ASTR + quad * 8);
  const v8s b1 = *(const v8s*)(A + (cl * 4 + quad) * ASTR + 64);  // pad cols
#pragma unroll
  for (int t = 0; t < NT; ++t) {
    v4f a = bias4[t];
    a = MFMA(Wf[t * 2 + 0], b0, a, 0, 0, 0);
    a = MFMA(Wf[t * 2 + 1], b1, a, 0, 0, 0);
    acc[t] = a;
  }
}

// LayerNorm(64)+ReLU, features in-lane; short4 (b64) writes.
__device__ __forceinline__ void lnT_write(short* Aw, int tb, int col, int quad,
                                          v4f* acc, const v4f* g4,
                                          const v4f* be4) {
  float mu = 0.f, sq = 0.f;
#pragma unroll
  for (int t = 0; t < 4; ++t)
#pragma unroll
    for (int r = 0; r < 4; ++r) {
      mu += acc[t][r];
      sq = fmaf(acc[t][r], acc[t][r], sq);
    }
  mu += __shfl_xor(mu, 16); mu += __shfl_xor(mu, 32);
  sq += __shfl_xor(sq, 16); sq += __shfl_xor(sq, 32);
  mu *= (1.0f / 64.0f);
  const float var = sq * (1.0f / 64.0f) - mu * mu;
  const float rs = rsqrtf(var + 1e-5f);
#pragma unroll
  for (int t = 0; t < 4; ++t) {
    short4 s;
#pragma unroll
    for (int r = 0; r < 4; ++r) {
      float v = fmaf((acc[t][r] - mu) * rs, g4[t][r], be4[t][r]);
      ((short*)&s)[r] = bfb(fmaxf(v, 0.f));
    }
    *(short4*)(Aw + (tb + col) * ASTR + t * 16 + quad * 4) = s;
  }
}

template <int NT>
__device__ __forceinline__ void plainT_write(short* Aw, int tb, int col,
                                             int quad, v4f* acc) {
#pragma unroll
  for (int t = 0; t < NT; ++t) {
    short4 s;
#pragma unroll
    for (int r = 0; r < 4; ++r) ((short*)&s)[r] = bfb(acc[t][r]);
    *(short4*)(Aw + (tb + col) * ASTR + t * 16 + quad * 4) = s;
  }
}

// ---- kF: the whole network, one wave = 4 clusters, zero barriers ----
__global__ void __launch_bounds__(128, 2)
kF(const float* __restrict__ x, const int* __restrict__ batch,
   const short* __restrict__ wsW,
   const float* __restrict__ pb1, const float* __restrict__ pg,
   const float* __restrict__ pbe,
   const float* __restrict__ b1a, const float* __restrict__ ga,
   const float* __restrict__ bea, const float* __restrict__ b2a,
   const float* __restrict__ b1b, const float* __restrict__ gb,
   const float* __restrict__ beb, const float* __restrict__ b2b,
   const float* __restrict__ b1c, const float* __restrict__ gc_,
   const float* __restrict__ bec, const float* __restrict__ b2c,
   const float* __restrict__ ob1, const float* __restrict__ og,
   const float* __restrict__ obe, const float* __restrict__ ob2,
   float* __restrict__ out, int C) {
  __shared__ __align__(16) short act[2 * 80 * ASTR];   // 23040 B
  const int tid = threadIdx.x;
  const int lane = tid & 63;
  const int wave = tid >> 6;
  const int col = lane & 15;
  const int quad = lane >> 4;
  const int cbase = blockIdx.x * 8 + wave * 4;
  if (cbase >= C) return;
  const int nc = min(4, C - cbase);
  const int nrows = nc * 20;
  const int ntiles = (nrows + 15) >> 4;
  short* A = act + wave * 80 * ASTR;

  // ---- pre-MLP stage 1: 16(pad32) -> 64, LN, ReLU ----
  // B-fragment loaded DIRECTLY from global x (no LDS staging stage):
  // quads 0/1: features quad*8..+7 of node T*16+col = two contiguous
  // float4 loads; quads 2/3: K-pad zeros in-register (PW1 rows 16..31 = 0).
  {
    v8s Wf[4]; v4f b4[4], g4[4], be4[4];
#pragma unroll
    for (int t = 0; t < 4; ++t) {
      Wf[t] = *(const v8s*)(wsW + OFF_PW1 + (t * 16 + col) * 32 + quad * 8);
      b4[t]  = *(const v4f*)(pb1 + t * 16 + quad * 4);
      g4[t]  = *(const v4f*)(pg  + t * 16 + quad * 4);
      be4[t] = *(const v4f*)(pbe + t * 16 + quad * 4);
    }
    const float4* x4 = (const float4*)x;
    const long nb = (long)cbase * 20;
    for (int T = 0; T < ntiles; ++T) {
      const int node = T * 16 + col;
      v8s b = {0, 0, 0, 0, 0, 0, 0, 0};
      if (quad < 2 && node < nrows) {
        const float4 v0 = x4[(nb + node) * 4 + quad * 2];
        const float4 v1 = x4[(nb + node) * 4 + quad * 2 + 1];
        b[0] = bfb(v0.x); b[1] = bfb(v0.y); b[2] = bfb(v0.z); b[3] = bfb(v0.w);
        b[4] = bfb(v1.x); b[5] = bfb(v1.y); b[6] = bfb(v1.z); b[7] = bfb(v1.w);
      }
      v4f acc[4];
#pragma unroll
      for (int t = 0; t < 4; ++t) acc[t] = MFMA(Wf[t], b, b4[t], 0, 0, 0);
      lnT_write(A, T * 16, col, quad, acc, g4, be4);
    }
  }

  // (pre-MLP stage 2 fused into layer 0's W1 -- see kT blocks 1/2)

  // ---- 3 subgraph layers (R12's array-of-pointers form) ----
  const float* fb = (const float*)(wsW + OFF_FB);   // fused bias for L0-W1
  const float* B1p[3] = {fb, b1b, b1c};
  const float* Gp[3]  = {ga, gb, gc_};
  const float* BEp[3] = {bea, beb, bec};
  const float* B2p[3] = {b2a, b2b, b2c};

  for (int L = 0; L < 3; ++L) {
    v8s W1f[8], W2f[4];
    v4f b14[4], g4[4], be4[4], b24[2];
    const short* w1 = wsW + OFF_LW1(L);
    const short* w2 = wsW + OFF_LW2(L);
#pragma unroll
    for (int t = 0; t < 4; ++t) {
#pragma unroll
      for (int ks = 0; ks < 2; ++ks)
        W1f[t * 2 + ks] = *(const v8s*)(w1 + (t * 16 + col) * 64 + ks * 32 + quad * 8);
      b14[t] = *(const v4f*)(B1p[L] + t * 16 + quad * 4);
      g4[t]  = *(const v4f*)(Gp[L]  + t * 16 + quad * 4);
      be4[t] = *(const v4f*)(BEp[L] + t * 16 + quad * 4);
    }
#pragma unroll
    for (int t = 0; t < 2; ++t) {
#pragma unroll
      for (int ks = 0; ks < 2; ++ks)
        W2f[t * 2 + ks] = *(const v8s*)(w2 + (t * 16 + col) * 64 + ks * 32 + quad * 8);
      b24[t] = *(const v4f*)(B2p[L] + t * 16 + quad * 4);
    }
    for (int T = 0; T < ntiles; ++T) {
      v4f acc[4];
      if (L == 0)
        mmT<4, 2>(A, T * 16, W1f, b14, col, quad, acc);
      else
        mmT_split<4>(A, T * 16, W1f, b14, col, quad, acc);
      lnT_write(A, T * 16, col, quad, acc, g4, be4);
      v4f h[2];
      mmT<2, 2>(A, T * 16, W2f, b24, col, quad, h);
      plainT_write<2>(A, T * 16, col, quad, h);
    }
    // ---- intra-wave pooling: 4 clusters x 16 uint-cols ----
    {
      const int cl = quad, jp = col;
      if (cl < nc) {
        const uint* AU = (const uint*)A;
        float m0 = -3.4e38f, m1 = -3.4e38f;
#pragma unroll
        for (int r = 0; r < 20; ++r) {
          const uint v = AU[(cl * 20 + r) * (ASTR / 2) + jp];
          m0 = fmaxf(m0, __builtin_bit_cast(float, v << 16));
          m1 = fmaxf(m1, __builtin_bit_cast(float, v & 0xFFFF0000u));
        }
        const uint pv = (uint)(unsigned short)bfb(m0) |
                        ((uint)(unsigned short)bfb(m1) << 16);
        uint* AW = (uint*)A;
        if (L < 2) {
          // compact: row cl*4+u's pad uints 32..35 hold pooled uints 4u..4u+3
          AW[(cl * 4 + (jp >> 2)) * (ASTR / 2) + 32 + (jp & 3)] = pv;
        } else {
          // segmax(concat[h,pooled]) == [pooled,pooled] -> rows 0..3 = pooled
          AW[cl * (ASTR / 2) + jp] = pv;
          AW[cl * (ASTR / 2) + 16 + jp] = pv;
        }
      }
    }
  }

  // ---- fused output MLP on rows 0..15 (rows 0..nc-1 valid) ----
  {
    v8s Wf[8]; v4f b4[4], g4[4], be4[4];
#pragma unroll
    for (int t = 0; t < 4; ++t) {
#pragma unroll
      for (int ks = 0; ks < 2; ++ks)
        Wf[t * 2 + ks] = *(const v8s*)(wsW + OFF_OW1 + (t * 16 + col) * 64 + ks * 32 + quad * 8);
      b4[t]  = *(const v4f*)(ob1 + t * 16 + quad * 4);
      g4[t]  = *(const v4f*)(og  + t * 16 + quad * 4);
      be4[t] = *(const v4f*)(obe + t * 16 + quad * 4);
    }
    v4f acc[4];
    mmT<4, 2>(A, 0, Wf, b4, col, quad, acc);
    lnT_write(A, 0, col, quad, acc, g4, be4);
  }
  {
    v4f acc[8];
    const v8s bb0 = *(const v8s*)(A + col * ASTR + quad * 8);
    const v8s bb1 = *(const v8s*)(A + col * ASTR + 32 + quad * 8);
#pragma unroll
    for (int half = 0; half < 2; ++half) {
      v8s Wf[8];
#pragma unroll
      for (int t = 0; t < 4; ++t)
#pragma unroll
        for (int ks = 0; ks < 2; ++ks)
          Wf[t * 2 + ks] = *(const v8s*)(wsW + OFF_OW2 +
                             ((half * 4 + t) * 16 + col) * 64 + ks * 32 + quad * 8);
#pragma unroll
      for (int t = 0; t < 4; ++t) {
        v4f a = *(const v4f*)(ob2 + (half * 4 + t) * 16 + quad * 4);
        a = MFMA(Wf[t * 2], bb0, a, 0, 0, 0);
        a = MFMA(Wf[t * 2 + 1], bb1, a, 0, 0, 0);
        acc[half * 4 + t] = a;
      }
    }
    // L2 norm over 128 feats (32 in-lane + cross-quad)
    float sq = 0.f;
#pragma unroll
    for (int t = 0; t < 8; ++t)
#pragma unroll
      for (int r = 0; r < 4; ++r) sq = fmaf(acc[t][r], acc[t][r], sq);
    sq += __shfl_xor(sq, 16); sq += __shfl_xor(sq, 32);
    const float inv = 1.0f / fmaxf(sqrtf(sq), 1e-12f);
    if (col < nc) {
      const long gcl = cbase + col;
#pragma unroll
      for (int t = 0; t < 8; ++t) {
        float4 v = {acc[t][0] * inv, acc[t][1] * inv,
                    acc[t][2] * inv, acc[t][3] * inv};
        *(float4*)(out + gcl * 128 + t * 16 + quad * 4) = v;
      }
      if (quad == 0) out[(long)C * 128 + gcl] = (float)batch[gcl * 20];
    }
  }
}

extern "C" void kernel_launch(void* const* d_in, const int* in_sizes, int n_in,
                              void* d_out, int out_size, void* d_ws, size_t ws_size,
                              hipStream_t stream) {
  const float* x     = (const float*)d_in[0];
  const int*   batch = (const int*)d_in[2];
  const float* pw1 = (const float*)d_in[3];
  const float* pb1 = (const float*)d_in[4];
  const float* pg  = (const float*)d_in[5];
  const float* pbe = (const float*)d_in[6];
  const float* pw2 = (const float*)d_in[7];
  const float* pb2 = (const float*)d_in[8];
  const float* w1a = (const float*)d_in[9];
  const float* b1a = (const float*)d_in[10];
  const float* ga  = (const float*)d_in[11];
  const float* bea = (const float*)d_in[12];
  const float* w2a = (const float*)d_in[13];
  const float* b2a = (const float*)d_in[14];
  const float* w1b = (const float*)d_in[15];
  const float* b1b = (const float*)d_in[16];
  const float* gb  = (const float*)d_in[17];
  const float* beb = (const float*)d_in[18];
  const float* w2b = (const float*)d_in[19];
  const float* b2b = (const float*)d_in[20];
  const float* w1c = (const float*)d_in[21];
  const float* b1c = (const float*)d_in[22];
  const float* gc  = (const float*)d_in[23];
  const float* bec = (const float*)d_in[24];
  const float* w2c = (const float*)d_in[25];
  const float* b2c = (const float*)d_in[26];
  const float* ow1 = (const float*)d_in[27];
  const float* ob1 = (const float*)d_in[28];
  const float* og  = (const float*)d_in[29];
  const float* obe = (const float*)d_in[30];
  const float* ow2 = (const float*)d_in[31];
  const float* ob2 = (const float*)d_in[32];

  const int N = in_sizes[0] / 16;
  const int C = N / 20;
  short* ws16 = (short*)d_ws;
  float* out = (float*)d_out;

  hipLaunchKernelGGL(kT, dim3(10), dim3(256), 0, stream,
                     pw1, pw2, w1a, w2a, w1b, w2b, w1c, w2c, ow1, ow2,
                     pb2, b1a, ws16);

  const int blocks = (C + 7) / 8;   // 8 clusters per block (2 waves x 4)
  hipLaunchKernelGGL(kF, dim3(blocks), dim3(128), 0, stream,
                     x, batch, (const short*)ws16,
                     pb1, pg, pbe,
                     b1a, ga, bea, b2a,
                     b1b, gb, beb, b2b,
                     b1c, gc, bec, b2c,
                     ob1, og, obe, ob2,
                     out, C);
}

// Round 15
// 282.868 us; speedup vs baseline: 1.1383x; 1.0709x over previous
//
#include <hip/hip_runtime.h>

// ---------------------------------------------------------------------------
// Barrier-free wave-autonomous design, TRANSPOSED MFMA epilogue.
// Round 15 = R14 base (155.8us kF: fusion + compact pool + direct-global
// pre1) + OUTPUT-MLP CONSOLIDATION. The per-wave out-MLP tile had only 4
// valid of 16 columns, duplicated in both waves. Now: layer-2 pooling
// writes each wave's 4 pooled rows to a shared outT[16] tile; ONE
// __syncthreads(); wave 0 runs the out-MLP for all 8 clusters (8/16 valid),
// wave 1 exits early. Same arithmetic; out-MLP cost per block halves.
// Junk rows 8..15 zero-filled (LN is per-column, so junk is contained).
// ---------------------------------------------------------------------------

#define ASTR 72   // act row stride in shorts (64 feats + 8 pad = pooled slot)

typedef short v8s __attribute__((ext_vector_type(8)));
typedef float v4f __attribute__((ext_vector_type(4)));

#define MFMA __builtin_amdgcn_mfma_f32_16x16x32_bf16

// ws layout (offsets in shorts)
#define OFF_PW1 0                        // 64 x 32 (K=16 zero-padded to 32)
#define OFF_FB  2048                     // 64 f32 fused bias (in old PW2 slot)
#define OFF_LW1(L) (6144 + (L) * 6144)   // 64 x 64  (L=0 holds FUSED pw2@w1a)
#define OFF_LW2(L) (OFF_LW1(L) + 4096)   // 32 x 64
#define OFF_OW1 24576                    // 64 x 64
#define OFF_OW2 28672                    // 128 x 64   (end = 36864 shorts)

__device__ __forceinline__ short bfb(float v) {
  __bf16 b = (__bf16)v;
  return __builtin_bit_cast(short, b);
}

// ---- kT: transpose weights into bf16 B-fragment layout in ws ----
__global__ void kT(const float* __restrict__ pw1, const float* __restrict__ pw2,
                   const float* __restrict__ w1a, const float* __restrict__ w2a,
                   const float* __restrict__ w1b, const float* __restrict__ w2b,
                   const float* __restrict__ w1c, const float* __restrict__ w2c,
                   const float* __restrict__ ow1, const float* __restrict__ ow2,
                   const float* __restrict__ pb2, const float* __restrict__ b1a,
                   short* __restrict__ ws) {
  if (blockIdx.x == 1) {
    float* fb = (float*)(ws + OFF_FB);
    for (int f = threadIdx.x; f < 64; f += blockDim.x) {
      float s = b1a[f];
      for (int m = 0; m < 64; ++m) s = fmaf(pb2[m], w1a[m * 64 + f], s);
      fb[f] = s;
    }
    return;
  }
  if (blockIdx.x == 2) {
    const int off = OFF_LW1(0);
    const int total = 64 * 8;
    for (int i = threadIdx.x; i < total; i += blockDim.x) {
      const int f = i % 64;
      const int kq = i / 64;
      v8s h;
#pragma unroll
      for (int j = 0; j < 8; ++j) {
        const int k = kq * 8 + j;
        float s = 0.f;
        for (int m = 0; m < 64; ++m) s = fmaf(pw2[k * 64 + m], w1a[m * 64 + f], s);
        h[j] = bfb(s);
      }
      *(v8s*)(ws + off + f * 64 + kq * 8) = h;
    }
    return;
  }
  const float* W; int K, F, Kpad, off;
  switch (blockIdx.x) {
    case 0: W = pw1; K = 16; F = 64;  Kpad = 32; off = OFF_PW1; break;
    case 3: W = w2a; K = 64; F = 32;  Kpad = 64; off = OFF_LW2(0); break;
    case 4: W = w1b; K = 64; F = 64;  Kpad = 64; off = OFF_LW1(1); break;
    case 5: W = w2b; K = 64; F = 32;  Kpad = 64; off = OFF_LW2(1); break;
    case 6: W = w1c; K = 64; F = 64;  Kpad = 64; off = OFF_LW1(2); break;
    case 7: W = w2c; K = 64; F = 32;  Kpad = 64; off = OFF_LW2(2); break;
    case 8: W = ow1; K = 64; F = 64;  Kpad = 64; off = OFF_OW1; break;
    default: W = ow2; K = 64; F = 128; Kpad = 64; off = OFF_OW2; break;
  }
  const int total = F * (Kpad >> 3);
  for (int i = threadIdx.x; i < total; i += blockDim.x) {
    const int f = i % F;
    const int kq = i / F;
    v8s h;
#pragma unroll
    for (int j = 0; j < 8; ++j) {
      const int k = kq * 8 + j;
      h[j] = bfb((k < K) ? W[k * F + f] : 0.f);
    }
    *(v8s*)(ws + off + f * Kpad + kq * 8) = h;
  }
}

// Transposed matmul over one 16-node tile: acc[t] covers features t*16..+15.
template <int NT, int KS>
__device__ __forceinline__ void mmT(const short* A, int tb, const v8s* Wf,
                                    const v4f* bias4, int col, int quad,
                                    v4f* acc) {
#pragma unroll
  for (int t = 0; t < NT; ++t) acc[t] = bias4[t];
#pragma unroll
  for (int ks = 0; ks < KS; ++ks) {
    const v8s b = *(const v8s*)(A + (tb + col) * ASTR + ks * 32 + quad * 8);
#pragma unroll
    for (int t = 0; t < NT; ++t)
      acc[t] = MFMA(Wf[t * KS + ks], b, acc[t], 0, 0, 0);
  }
}

// Split matmul: k=0..31 from act row (h), k=32..63 from pooled pad (bcast).
template <int NT>
__device__ __forceinline__ void mmT_split(const short* A, int tb,
                                          const v8s* Wf, const v4f* bias4,
                                          int col, int quad, v4f* acc) {
  const int node = tb + col;
  const int cl = (node * 205) >> 12;                 // node/20 for node<80
  const v8s b0 = *(const v8s*)(A + node * ASTR + quad * 8);
  const v8s b1 = *(const v8s*)(A + (cl * 4 + quad) * ASTR + 64);  // pad cols
#pragma unroll
  for (int t = 0; t < NT; ++t) {
    v4f a = bias4[t];
    a = MFMA(Wf[t * 2 + 0], b0, a, 0, 0, 0);
    a = MFMA(Wf[t * 2 + 1], b1, a, 0, 0, 0);
    acc[t] = a;
  }
}

// LayerNorm(64)+ReLU, features in-lane; short4 (b64) writes.
__device__ __forceinline__ void lnT_write(short* Aw, int tb, int col, int quad,
                                          v4f* acc, const v4f* g4,
                                          const v4f* be4) {
  float mu = 0.f, sq = 0.f;
#pragma unroll
  for (int t = 0; t < 4; ++t)
#pragma unroll
    for (int r = 0; r < 4; ++r) {
      mu += acc[t][r];
      sq = fmaf(acc[t][r], acc[t][r], sq);
    }
  mu += __shfl_xor(mu, 16); mu += __shfl_xor(mu, 32);
  sq += __shfl_xor(sq, 16); sq += __shfl_xor(sq, 32);
  mu *= (1.0f / 64.0f);
  const float var = sq * (1.0f / 64.0f) - mu * mu;
  const float rs = rsqrtf(var + 1e-5f);
#pragma unroll
  for (int t = 0; t < 4; ++t) {
    short4 s;
#pragma unroll
    for (int r = 0; r < 4; ++r) {
      float v = fmaf((acc[t][r] - mu) * rs, g4[t][r], be4[t][r]);
      ((short*)&s)[r] = bfb(fmaxf(v, 0.f));
    }
    *(short4*)(Aw + (tb + col) * ASTR + t * 16 + quad * 4) = s;
  }
}

template <int NT>
__device__ __forceinline__ void plainT_write(short* Aw, int tb, int col,
                                             int quad, v4f* acc) {
#pragma unroll
  for (int t = 0; t < NT; ++t) {
    short4 s;
#pragma unroll
    for (int r = 0; r < 4; ++r) ((short*)&s)[r] = bfb(acc[t][r]);
    *(short4*)(Aw + (tb + col) * ASTR + t * 16 + quad * 4) = s;
  }
}

// ---- kF: the whole network; one wave = 4 clusters; ONE barrier ----
__global__ void __launch_bounds__(128, 2)
kF(const float* __restrict__ x, const int* __restrict__ batch,
   const short* __restrict__ wsW,
   const float* __restrict__ pb1, const float* __restrict__ pg,
   const float* __restrict__ pbe,
   const float* __restrict__ b1a, const float* __restrict__ ga,
   const float* __restrict__ bea, const float* __restrict__ b2a,
   const float* __restrict__ b1b, const float* __restrict__ gb,
   const float* __restrict__ beb, const float* __restrict__ b2b,
   const float* __restrict__ b1c, const float* __restrict__ gc_,
   const float* __restrict__ bec, const float* __restrict__ b2c,
   const float* __restrict__ ob1, const float* __restrict__ og,
   const float* __restrict__ obe, const float* __restrict__ ob2,
   float* __restrict__ out, int C) {
  __shared__ __align__(16) short act[2 * 80 * ASTR];   // 23040 B
  __shared__ __align__(16) short outT[16 * ASTR];      // 2304 B shared tile
  const int tid = threadIdx.x;
  const int lane = tid & 63;
  const int wave = tid >> 6;
  const int col = lane & 15;
  const int quad = lane >> 4;
  const int blockBase = blockIdx.x * 8;
  if (blockBase >= C) return;              // whole block out of range only
  const int cbase = blockBase + wave * 4;
  const int nc = min(4, max(0, C - cbase));
  const int nrows = nc * 20;
  const int ntiles = (nrows + 15) >> 4;
  short* A = act + wave * 80 * ASTR;

  // wave 0: zero junk rows 8..15 of outT (uints 288..575) before barrier
  if (wave == 0) {
    uint* OTu = (uint*)outT;
    for (int i = lane; i < 288; i += 64) OTu[288 + i] = 0u;
  }

  if (nc > 0) {
    // ---- pre-MLP stage 1: 16(pad32) -> 64, LN, ReLU (direct-global B) ----
    {
      v8s Wf[4]; v4f b4[4], g4[4], be4[4];
#pragma unroll
      for (int t = 0; t < 4; ++t) {
        Wf[t] = *(const v8s*)(wsW + OFF_PW1 + (t * 16 + col) * 32 + quad * 8);
        b4[t]  = *(const v4f*)(pb1 + t * 16 + quad * 4);
        g4[t]  = *(const v4f*)(pg  + t * 16 + quad * 4);
        be4[t] = *(const v4f*)(pbe + t * 16 + quad * 4);
      }
      const float4* x4 = (const float4*)x;
      const long nb = (long)cbase * 20;
      for (int T = 0; T < ntiles; ++T) {
        const int node = T * 16 + col;
        v8s b = {0, 0, 0, 0, 0, 0, 0, 0};
        if (quad < 2 && node < nrows) {
          const float4 v0 = x4[(nb + node) * 4 + quad * 2];
          const float4 v1 = x4[(nb + node) * 4 + quad * 2 + 1];
          b[0] = bfb(v0.x); b[1] = bfb(v0.y); b[2] = bfb(v0.z); b[3] = bfb(v0.w);
          b[4] = bfb(v1.x); b[5] = bfb(v1.y); b[6] = bfb(v1.z); b[7] = bfb(v1.w);
        }
        v4f acc[4];
#pragma unroll
        for (int t = 0; t < 4; ++t) acc[t] = MFMA(Wf[t], b, b4[t], 0, 0, 0);
        lnT_write(A, T * 16, col, quad, acc, g4, be4);
      }
    }

    // ---- 3 subgraph layers ----
    const float* fb = (const float*)(wsW + OFF_FB);   // fused bias for L0-W1
    const float* B1p[3] = {fb, b1b, b1c};
    const float* Gp[3]  = {ga, gb, gc_};
    const float* BEp[3] = {bea, beb, bec};
    const float* B2p[3] = {b2a, b2b, b2c};

    for (int L = 0; L < 3; ++L) {
      v8s W1f[8], W2f[4];
      v4f b14[4], g4[4], be4[4], b24[2];
      const short* w1 = wsW + OFF_LW1(L);
      const short* w2 = wsW + OFF_LW2(L);
#pragma unroll
      for (int t = 0; t < 4; ++t) {
#pragma unroll
        for (int ks = 0; ks < 2; ++ks)
          W1f[t * 2 + ks] = *(const v8s*)(w1 + (t * 16 + col) * 64 + ks * 32 + quad * 8);
        b14[t] = *(const v4f*)(B1p[L] + t * 16 + quad * 4);
        g4[t]  = *(const v4f*)(Gp[L]  + t * 16 + quad * 4);
        be4[t] = *(const v4f*)(BEp[L] + t * 16 + quad * 4);
      }
#pragma unroll
      for (int t = 0; t < 2; ++t) {
#pragma unroll
        for (int ks = 0; ks < 2; ++ks)
          W2f[t * 2 + ks] = *(const v8s*)(w2 + (t * 16 + col) * 64 + ks * 32 + quad * 8);
        b24[t] = *(const v4f*)(B2p[L] + t * 16 + quad * 4);
      }
      for (int T = 0; T < ntiles; ++T) {
        v4f acc[4];
        if (L == 0)
          mmT<4, 2>(A, T * 16, W1f, b14, col, quad, acc);
        else
          mmT_split<4>(A, T * 16, W1f, b14, col, quad, acc);
        lnT_write(A, T * 16, col, quad, acc, g4, be4);
        v4f h[2];
        mmT<2, 2>(A, T * 16, W2f, b24, col, quad, h);
        plainT_write<2>(A, T * 16, col, quad, h);
      }
      // ---- intra-wave pooling: 4 clusters x 16 uint-cols ----
      {
        const int cl = quad, jp = col;
        if (cl < nc) {
          const uint* AU = (const uint*)A;
          float m0 = -3.4e38f, m1 = -3.4e38f;
#pragma unroll
          for (int r = 0; r < 20; ++r) {
            const uint v = AU[(cl * 20 + r) * (ASTR / 2) + jp];
            m0 = fmaxf(m0, __builtin_bit_cast(float, v << 16));
            m1 = fmaxf(m1, __builtin_bit_cast(float, v & 0xFFFF0000u));
          }
          const uint pv = (uint)(unsigned short)bfb(m0) |
                          ((uint)(unsigned short)bfb(m1) << 16);
          if (L < 2) {
            uint* AW = (uint*)A;
            // compact: row cl*4+u's pad uints 32..35 hold pooled 4u..4u+3
            AW[(cl * 4 + (jp >> 2)) * (ASTR / 2) + 32 + (jp & 3)] = pv;
          } else {
            // layer 2: pooled rows go to the SHARED outT tile, row wave*4+cl
            uint* OTu = (uint*)outT;
            OTu[(wave * 4 + cl) * (ASTR / 2) + jp] = pv;
            OTu[(wave * 4 + cl) * (ASTR / 2) + 16 + jp] = pv;
          }
        }
      }
    }
  }

  __syncthreads();            // outT complete (both waves' pooled rows)
  if (wave != 0) return;      // wave 1 done: out-MLP consolidated in wave 0

  // ---- fused output MLP on outT rows 0..15 (rows 0..ncb-1 valid) ----
  const int ncb = min(8, C - blockBase);
  {
    v8s Wf[8]; v4f b4[4], g4[4], be4[4];
#pragma unroll
    for (int t = 0; t < 4; ++t) {
#pragma unroll
      for (int ks = 0; ks < 2; ++ks)
        Wf[t * 2 + ks] = *(const v8s*)(wsW + OFF_OW1 + (t * 16 + col) * 64 + ks * 32 + quad * 8);
      b4[t]  = *(const v4f*)(ob1 + t * 16 + quad * 4);
      g4[t]  = *(const v4f*)(og  + t * 16 + quad * 4);
      be4[t] = *(const v4f*)(obe + t * 16 + quad * 4);
    }
    v4f acc[4];
    mmT<4, 2>(outT, 0, Wf, b4, col, quad, acc);
    lnT_write(outT, 0, col, quad, acc, g4, be4);
  }
  {
    v4f acc[8];
    const v8s bb0 = *(const v8s*)(outT + col * ASTR + quad * 8);
    const v8s bb1 = *(const v8s*)(outT + col * ASTR + 32 + quad * 8);
#pragma unroll
    for (int half = 0; half < 2; ++half) {
      v8s Wf[8];
#pragma unroll
      for (int t = 0; t < 4; ++t)
#pragma unroll
        for (int ks = 0; ks < 2; ++ks)
          Wf[t * 2 + ks] = *(const v8s*)(wsW + OFF_OW2 +
                             ((half * 4 + t) * 16 + col) * 64 + ks * 32 + quad * 8);
#pragma unroll
      for (int t = 0; t < 4; ++t) {
        v4f a = *(const v4f*)(ob2 + (half * 4 + t) * 16 + quad * 4);
        a = MFMA(Wf[t * 2], bb0, a, 0, 0, 0);
        a = MFMA(Wf[t * 2 + 1], bb1, a, 0, 0, 0);
        acc[half * 4 + t] = a;
      }
    }
    // L2 norm over 128 feats (32 in-lane + cross-quad)
    float sq = 0.f;
#pragma unroll
    for (int t = 0; t < 8; ++t)
#pragma unroll
      for (int r = 0; r < 4; ++r) sq = fmaf(acc[t][r], acc[t][r], sq);
    sq += __shfl_xor(sq, 16); sq += __shfl_xor(sq, 32);
    const float inv = 1.0f / fmaxf(sqrtf(sq), 1e-12f);
    if (col < ncb) {
      const long gcl = blockBase + col;
#pragma unroll
      for (int t = 0; t < 8; ++t) {
        float4 v = {acc[t][0] * inv, acc[t][1] * inv,
                    acc[t][2] * inv, acc[t][3] * inv};
        *(float4*)(out + gcl * 128 + t * 16 + quad * 4) = v;
      }
      if (quad == 0) out[(long)C * 128 + gcl] = (float)batch[gcl * 20];
    }
  }
}

extern "C" void kernel_launch(void* const* d_in, const int* in_sizes, int n_in,
                              void* d_out, int out_size, void* d_ws, size_t ws_size,
                              hipStream_t stream) {
  const float* x     = (const float*)d_in[0];
  const int*   batch = (const int*)d_in[2];
  const float* pw1 = (const float*)d_in[3];
  const float* pb1 = (const float*)d_in[4];
  const float* pg  = (const float*)d_in[5];
  const float* pbe = (const float*)d_in[6];
  const float* pw2 = (const float*)d_in[7];
  const float* pb2 = (const float*)d_in[8];
  const float* w1a = (const float*)d_in[9];
  const float* b1a = (const float*)d_in[10];
  const float* ga  = (const float*)d_in[11];
  const float* bea = (const float*)d_in[12];
  const float* w2a = (const float*)d_in[13];
  const float* b2a = (const float*)d_in[14];
  const float* w1b = (const float*)d_in[15];
  const float* b1b = (const float*)d_in[16];
  const float* gb  = (const float*)d_in[17];
  const float* beb = (const float*)d_in[18];
  const float* w2b = (const float*)d_in[19];
  const float* b2b = (const float*)d_in[20];
  const float* w1c = (const float*)d_in[21];
  const float* b1c = (const float*)d_in[22];
  const float* gc  = (const float*)d_in[23];
  const float* bec = (const float*)d_in[24];
  const float* w2c = (const float*)d_in[25];
  const float* b2c = (const float*)d_in[26];
  const float* ow1 = (const float*)d_in[27];
  const float* ob1 = (const float*)d_in[28];
  const float* og  = (const float*)d_in[29];
  const float* obe = (const float*)d_in[30];
  const float* ow2 = (const float*)d_in[31];
  const float* ob2 = (const float*)d_in[32];

  const int N = in_sizes[0] / 16;
  const int C = N / 20;
  short* ws16 = (short*)d_ws;
  float* out = (float*)d_out;

  hipLaunchKernelGGL(kT, dim3(10), dim3(256), 0, stream,
                     pw1, pw2, w1a, w2a, w1b, w2b, w1c, w2c, ow1, ow2,
                     pb2, b1a, ws16);

  const int blocks = (C + 7) / 8;   // 8 clusters per block (2 waves x 4)
  hipLaunchKernelGGL(kF, dim3(blocks), dim3(128), 0, stream,
                     x, batch, (const short*)ws16,
                     pb1, pg, pbe,
                     b1a, ga, bea, b2a,
                     b1b, gb, beb, b2b,
                     b1c, gc, bec, b2c,
                     ob1, og, obe, ob2,
                     out, C);
}